// Round 12
// baseline (1745.033 us; speedup 1.0000x reference)
//
#include <hip/hip_runtime.h>

// Problem constants
#define Bq 1024
#define Tq 512
#define Fq 64    // input features
#define Hq 128   // hidden

typedef _Float16 f16;
typedef f16 f16x2 __attribute__((ext_vector_type(2)));
typedef f16 f16x4 __attribute__((ext_vector_type(4)));
typedef f16 f16x8 __attribute__((ext_vector_type(8)));
typedef float f32x4 __attribute__((ext_vector_type(4)));

__device__ __forceinline__ float sigmoidf_(float x) {
    return 1.f / (1.f + __expf(-x));
}
__device__ __forceinline__ float tanhf_(float x) {
    return 1.f - 2.f / (__expf(2.f * x) + 1.f);
}

// compile-time-indexed select of one element of an f32x4 (3 cndmasks)
__device__ __forceinline__ float sel4(f32x4 v, int s) {
    float r = v.x;
    r = (s == 1) ? v.y : r;
    r = (s == 2) ? v.z : r;
    r = (s == 3) ? v.w : r;
    return r;
}

// ---------------- kernel A: decoder fold (one-time, tiny) ----------------
// W_comb = W_ih_dec @ W_out + W_hh_dec   (f16, [512][128])
// b_fold = b_ih_dec + b_hh_dec + W_ih_dec @ b_out   (f32, [512])
__global__ __launch_bounds__(256) void fold_kernel(
    const float* __restrict__ Wih_d, const float* __restrict__ Whh_d,
    const float* __restrict__ bih_d, const float* __restrict__ bhh_d,
    const float* __restrict__ Wout, const float* __restrict__ bout,
    f16* __restrict__ Wcomb, float* __restrict__ bfold)
{
    const int gid = blockIdx.x * 256 + threadIdx.x;   // 0..32767
    const int og = gid >> 6;          // gate row 0..511
    const int oh = (gid & 63) * 2;    // hh pair
    float ax = Whh_d[(size_t)og * Hq + oh];
    float ay = Whh_d[(size_t)og * Hq + oh + 1];
    for (int f = 0; f < Fq; ++f) {
        float w = Wih_d[(size_t)og * Fq + f];
        float2 o = *(const float2*)(Wout + (size_t)f * Hq + oh);
        ax += w * o.x; ay += w * o.y;
    }
    f16x2 r; r.x = (f16)ax; r.y = (f16)ay;
    *(f16x2*)(Wcomb + (size_t)og * Hq + oh) = r;
    if (gid < 512) {
        float b = bih_d[gid] + bhh_d[gid];
        for (int f = 0; f < Fq; ++f)
            b += Wih_d[(size_t)gid * Fq + f] * bout[f];
        bfold[gid] = b;
    }
}

// ---------------- kernel B: main recurrence ----------------
// 512 blocks x 512 threads (8 waves), TWO batch rows per block,
// 2 blocks/CU (__launch_bounds__(512,4) -> 4 waves/SIMD, 128-VGPR cap;
// r11 measured 112 VGPR so it fits). The co-resident block is
// barrier-INDEPENDENT: its waves fill our latency bubbles without adding
// barriers or shared LDS traffic (round 10's failure mode). Chip-wide MFMA
// doubles (N-waste 2/16) — affordable at 35% MfmaUtil.
// Per-block structure = r11: wave w owns gate-tiles {w,8+w,16+w,24+w} =
// i,f,g,o of units 16w..16w+15; in-register D-layout pointwise via sel4;
// folded decoder (K=128) with concurrent proj on waves 4-7; 1 barrier/step.
// Frag layouts (validated r4-r11):
//   A: lane l holds A[l&15][(l>>4)*8+j]   B: lane l holds B[(l>>4)*8+j][l&15]
//   D: lane l reg r = D[(l>>4)*4+r][l&15]
__global__ __launch_bounds__(512, 4)
void lstm_ae_kernel(
    const float* __restrict__ ts,
    const float* __restrict__ Wih_e, const float* __restrict__ Whh_e,
    const float* __restrict__ bih_e, const float* __restrict__ bhh_e,
    const float* __restrict__ Wout, const float* __restrict__ bout,
    const f16* __restrict__ Wcomb, const float* __restrict__ bfold,
    float* __restrict__ out)
{
    const int tid = threadIdx.x;
    const int bid = blockIdx.x;
    const int row0 = bid * 2;

    const int wv = tid >> 6;       // wave 0..7 (owns units wv*16..wv*16+15)
    const int ln = tid & 63;
    const int n16 = ln & 15;       // MFMA N col (batch col; <2 real)
    const int kg = ln >> 4;        // k-group 0..3 (D rows kg*4..kg*4+3)
    const int zr = n16 & 1;        // batch row alias for B-frag
    const bool act2 = (n16 < 2);
    const bool pw = (n16 < 8);     // pointwise-active lanes (32/wave)
    const int us = (n16 >> 1) & 3; // D-reg select for pointwise
    const int un = kg * 4 + us;    // pointwise unit (wv*16+un), col n16&1

    __shared__ alignas(16) f16 hT[2][2][144];        // h dbuf
    __shared__ alignas(16) f16 xS[2][2][8][76];      // x chunk dbuf
    __shared__ float errb[4][2];

    float c_ = 0.f;    // one unit (wv*16+un), one batch col (n16&1)
    float bs[4];       // bias for that unit, gates i,f,g,o

    // ===================== encoder setup =====================
    f16x8 wf[4][6];   // A-frags [gate][k-tile], 96 VGPR
#pragma unroll
    for (int g = 0; g < 4; ++g) {
        const int gr = g * 128 + wv * 16 + n16;
#pragma unroll
        for (int kt = 0; kt < 6; ++kt) {
            const int kc = kt * 32 + kg * 8;
            const float* src = (kt < 2)
                ? (Wih_e + (size_t)gr * Fq + kc)
                : (Whh_e + (size_t)gr * Hq + (kc - 64));
            float4 f0 = *(const float4*)src;
            float4 f1 = *(const float4*)(src + 4);
            f16x8 a;
            a[0] = (f16)f0.x; a[1] = (f16)f0.y; a[2] = (f16)f0.z; a[3] = (f16)f0.w;
            a[4] = (f16)f1.x; a[5] = (f16)f1.y; a[6] = (f16)f1.z; a[7] = (f16)f1.w;
            wf[g][kt] = a;
        }
        bs[g] = bih_e[g * 128 + wv * 16 + un] + bhh_e[g * 128 + wv * 16 + un];
    }

    // zero h buffer 0 (both rows)
    if (act2) {
        f16x4 z; z[0] = (f16)0.f; z[1] = (f16)0.f; z[2] = (f16)0.f; z[3] = (f16)0.f;
        *(f16x4*)(&hT[0][n16][wv * 16 + kg * 4]) = z;
    }
    // stage x chunk 0 (256 threads): thread -> (r, t8, fg)
    const int t2 = tid & 255;
    const int sr = t2 >> 7, st8 = (t2 >> 4) & 7, sfg = t2 & 15;
    if (tid < 256) {
        float4 v = *(const float4*)(ts + (size_t)(row0 + sr) * Tq * Fq +
                                    (size_t)st8 * Fq + sfg * 4);
        f16x4 h4; h4[0] = (f16)v.x; h4[1] = (f16)v.y; h4[2] = (f16)v.z; h4[3] = (f16)v.w;
        *(f16x4*)(&xS[0][sr][st8][sfg * 4]) = h4;
    }
    __syncthreads();

    // ===================== encoder: 512 steps, 1 barrier each ============
    float4 xpre;
    for (int t = 0; t < Tq; ++t) {
        const int buf = (t >> 3) & 1, tb = t & 7, par = t & 1;
        if (tid < 256 && tb == 0 && t < Tq - 8) {  // issue chunk c+1 loads
            xpre = *(const float4*)(ts + (size_t)(row0 + sr) * Tq * Fq +
                                    (size_t)(t + 8 + st8) * Fq + sfg * 4);
        }
        f16x8 bf[6];
        bf[0] = *(const f16x8*)(&xS[buf][zr][tb][kg * 8]);
        bf[1] = *(const f16x8*)(&xS[buf][zr][tb][32 + kg * 8]);
#pragma unroll
        for (int kt = 0; kt < 4; ++kt)
            bf[2 + kt] = *(const f16x8*)(&hT[par][zr][kt * 32 + kg * 8]);
        f32x4 acc[4];
#pragma unroll
        for (int g = 0; g < 4; ++g) acc[g] = (f32x4){0.f, 0.f, 0.f, 0.f};
#pragma unroll
        for (int kt = 0; kt < 6; ++kt)
#pragma unroll
            for (int g = 0; g < 4; ++g)
                acc[g] = __builtin_amdgcn_mfma_f32_16x16x32_f16(
                    wf[g][kt], bf[kt], acc[g], 0, 0, 0);
        {   // in-register pointwise: lanes n16<8, one (unit, col) each
            float gi = sel4(acc[0], us) + bs[0];
            float gf = sel4(acc[1], us) + bs[1];
            float gg = sel4(acc[2], us) + bs[2];
            float go = sel4(acc[3], us) + bs[3];
            float i_ = sigmoidf_(gi);
            float f_ = sigmoidf_(gf);
            float g_ = tanhf_(gg);
            float o_ = sigmoidf_(go);
            c_ = f_ * c_ + i_ * g_;
            if (pw)
                hT[par ^ 1][n16 & 1][wv * 16 + un] = (f16)(o_ * tanhf_(c_));
        }
        if (tid < 256 && tb == 7 && t != Tq - 1) {  // publish staged chunk
            f16x4 h4; h4[0] = (f16)xpre.x; h4[1] = (f16)xpre.y;
            h4[2] = (f16)xpre.z; h4[3] = (f16)xpre.w;
            *(f16x4*)(&xS[buf ^ 1][sr][st8][sfg * 4]) = h4;
        }
        __syncthreads();
    }

    // c_enc: pw lanes own unit wv*16+un of batch row n16&1
    if (pw) out[(size_t)(row0 + (n16 & 1)) * Hq + wv * 16 + un] = c_;

    // ===================== decoder setup =====================
    f16x8 wc[4][4];   // folded weights straight from ws: 16 x 16B loads
#pragma unroll
    for (int g = 0; g < 4; ++g) {
        const int gr = g * 128 + wv * 16 + n16;
#pragma unroll
        for (int kt = 0; kt < 4; ++kt)
            wc[g][kt] = *(const f16x8*)(Wcomb + (size_t)gr * Hq + kt * 32 + kg * 8);
        bs[g] = bfold[g * 128 + wv * 16 + un];
    }
    // proj A-frags (waves 4..7 use them; mt=wv&3 keeps addresses valid)
    const int mt = wv & 3;
    f16x8 wo[4];
#pragma unroll
    for (int kt = 0; kt < 4; ++kt) {
        const float* src = Wout + (size_t)(mt * 16 + n16) * Hq + kt * 32 + kg * 8;
        float4 f0 = *(const float4*)src;
        float4 f1 = *(const float4*)(src + 4);
        f16x8 a;
        a[0] = (f16)f0.x; a[1] = (f16)f0.y; a[2] = (f16)f0.z; a[3] = (f16)f0.w;
        a[4] = (f16)f1.x; a[5] = (f16)f1.y; a[6] = (f16)f1.z; a[7] = (f16)f1.w;
        wo[kt] = a;
    }
    float4 bo4 = *(const float4*)(bout + mt * 16 + kg * 4);
    float4 tsv = *(const float4*)(ts + (size_t)(row0 + zr) * Tq * Fq +
                                  (size_t)(Tq - 1) * Fq + mt * 16 + kg * 4);
    float err_ = 0.f;
    __syncthreads();

    // ===================== decoder: 512 steps, 1 barrier each ============
    for (int k = 0; k < Tq; ++k) {
        const int pk = k & 1;
        f16x8 bf[4];
#pragma unroll
        for (int kt = 0; kt < 4; ++kt)
            bf[kt] = *(const f16x8*)(&hT[pk][zr][kt * 32 + kg * 8]);
        f32x4 acc[4];
#pragma unroll
        for (int g = 0; g < 4; ++g) acc[g] = (f32x4){0.f, 0.f, 0.f, 0.f};
#pragma unroll
        for (int kt = 0; kt < 4; ++kt)
#pragma unroll
            for (int g = 0; g < 4; ++g)
                acc[g] = __builtin_amdgcn_mfma_f32_16x16x32_f16(
                    wc[g][kt], bf[kt], acc[g], 0, 0, 0);
        if (wv >= 4) {   // concurrent projection of h[pk] for rec_err
            f32x4 pacc = (f32x4){0.f, 0.f, 0.f, 0.f};
#pragma unroll
            for (int kt = 0; kt < 4; ++kt)
                pacc = __builtin_amdgcn_mfma_f32_16x16x32_f16(
                    wo[kt], bf[kt], pacc, 0, 0, 0);
            if (act2) {
                float a0 = pacc[0] + bo4.x, a1 = pacc[1] + bo4.y;
                float a2 = pacc[2] + bo4.z, a3 = pacc[3] + bo4.w;
                if (k == 0) {
                    float4 av; av.x = a0; av.y = a1; av.z = a2; av.w = a3;
                    *(float4*)(out + (size_t)Bq * Hq + Bq +
                               (size_t)(row0 + n16) * Fq + mt * 16 + kg * 4) = av;
                }
                err_ += fabsf(a0 * a0 - tsv.x * tsv.x);
                err_ += fabsf(a1 * a1 - tsv.y * tsv.y);
                err_ += fabsf(a2 * a2 - tsv.z * tsv.z);
                err_ += fabsf(a3 * a3 - tsv.w * tsv.w);
                if (k < Tq - 1)
                    tsv = *(const float4*)(ts + (size_t)(row0 + n16) * Tq * Fq +
                                           (size_t)(Tq - 2 - k) * Fq +
                                           mt * 16 + kg * 4);
            }
        }
        {   // in-register pointwise
            float gi = sel4(acc[0], us) + bs[0];
            float gf = sel4(acc[1], us) + bs[1];
            float gg = sel4(acc[2], us) + bs[2];
            float go = sel4(acc[3], us) + bs[3];
            float i_ = sigmoidf_(gi);
            float f_ = sigmoidf_(gf);
            float g_ = tanhf_(gg);
            float o_ = sigmoidf_(go);
            c_ = f_ * c_ + i_ * g_;
            if (pw)
                hT[pk ^ 1][n16 & 1][wv * 16 + un] = (f16)(o_ * tanhf_(c_));
        }
        __syncthreads();
    }

    // rec_err reduction: waves 4..7 hold per-(row,f-slice) partials
    if (wv >= 4) {
        err_ += __shfl_xor(err_, 16, 64);   // sum over kg bit 0
        err_ += __shfl_xor(err_, 32, 64);   // sum over kg bit 1
        if (kg == 0 && act2) errb[mt][n16] = err_;
    }
    __syncthreads();
    if (tid < 2) {
        float e = errb[0][tid] + errb[1][tid] + errb[2][tid] + errb[3][tid];
        out[(size_t)Bq * Hq + row0 + tid] = e;
    }
}

extern "C" void kernel_launch(void* const* d_in, const int* in_sizes, int n_in,
                              void* d_out, int out_size, void* d_ws, size_t ws_size,
                              hipStream_t stream) {
    const float* ts    = (const float*)d_in[0];
    const float* Wih_e = (const float*)d_in[1];
    const float* Whh_e = (const float*)d_in[2];
    const float* bih_e = (const float*)d_in[3];
    const float* bhh_e = (const float*)d_in[4];
    const float* Wih_d = (const float*)d_in[5];
    const float* Whh_d = (const float*)d_in[6];
    const float* bih_d = (const float*)d_in[7];
    const float* bhh_d = (const float*)d_in[8];
    const float* Wout  = (const float*)d_in[9];
    const float* bout  = (const float*)d_in[10];
    float* out = (float*)d_out;

    f16*   Wcomb = (f16*)d_ws;                                   // 128 KB
    float* bfold = (float*)((char*)d_ws + (size_t)512 * 128 * 2); // +2 KB

    hipLaunchKernelGGL(fold_kernel, dim3(128), dim3(256), 0, stream,
                       Wih_d, Whh_d, bih_d, bhh_d, Wout, bout, Wcomb, bfold);
    hipLaunchKernelGGL(lstm_ae_kernel, dim3(Bq / 2), dim3(512), 0, stream,
                       ts, Wih_e, Whh_e, bih_e, bhh_e,
                       Wout, bout, Wcomb, bfold, out);
}

// Round 13
// 1471.445 us; speedup vs baseline: 1.1859x; 1.1859x over previous
//
#include <hip/hip_runtime.h>

// Problem constants
#define Bq 1024
#define Tq 512
#define Fq 64    // input features
#define Hq 128   // hidden

typedef _Float16 f16;
typedef f16 f16x2 __attribute__((ext_vector_type(2)));
typedef f16 f16x4 __attribute__((ext_vector_type(4)));
typedef f16 f16x8 __attribute__((ext_vector_type(8)));
typedef float f32x4 __attribute__((ext_vector_type(4)));

__device__ __forceinline__ float sigmoidf_(float x) {
    return 1.f / (1.f + __expf(-x));
}
__device__ __forceinline__ float tanhf_(float x) {
    return 1.f - 2.f / (__expf(2.f * x) + 1.f);
}

// compile-time-indexed select of one element of an f32x4 (3 cndmasks)
__device__ __forceinline__ float sel4(f32x4 v, int s) {
    float r = v.x;
    r = (s == 1) ? v.y : r;
    r = (s == 2) ? v.z : r;
    r = (s == 3) ? v.w : r;
    return r;
}

// ---------------- kernel A: decoder fold (one-time, tiny) ----------------
// W_comb = W_ih_dec @ W_out + W_hh_dec   (f16, [512][128])
// b_fold = b_ih_dec + b_hh_dec + W_ih_dec @ b_out   (f32, [512])
__global__ __launch_bounds__(256) void fold_kernel(
    const float* __restrict__ Wih_d, const float* __restrict__ Whh_d,
    const float* __restrict__ bih_d, const float* __restrict__ bhh_d,
    const float* __restrict__ Wout, const float* __restrict__ bout,
    f16* __restrict__ Wcomb, float* __restrict__ bfold)
{
    const int gid = blockIdx.x * 256 + threadIdx.x;   // 0..32767
    const int og = gid >> 6;          // gate row 0..511
    const int oh = (gid & 63) * 2;    // hh pair
    float ax = Whh_d[(size_t)og * Hq + oh];
    float ay = Whh_d[(size_t)og * Hq + oh + 1];
    for (int f = 0; f < Fq; ++f) {
        float w = Wih_d[(size_t)og * Fq + f];
        float2 o = *(const float2*)(Wout + (size_t)f * Hq + oh);
        ax += w * o.x; ay += w * o.y;
    }
    f16x2 r; r.x = (f16)ax; r.y = (f16)ay;
    *(f16x2*)(Wcomb + (size_t)og * Hq + oh) = r;
    if (gid < 512) {
        float b = bih_d[gid] + bhh_d[gid];
        for (int f = 0; f < Fq; ++f)
            b += Wih_d[(size_t)gid * Fq + f] * bout[f];
        bfold[gid] = b;
    }
}

// ---------------- kernel B: main recurrence ----------------
// 512 blocks x 512 threads (8 waves), TWO batch rows per block.
// Allocator spec: __launch_bounds__(512) + amdgpu_waves_per_eu(2) — the
// ONLY spec that never spilled (r9/r11: 108-112 VGPR). 112 <= 128 means
// the HW fits 2 blocks/CU naturally (4 waves/SIMD); the co-resident block
// is barrier-independent and fills our latency bubbles. r12's
// __launch_bounds__(512,4) made the allocator clamp to 64 VGPR + spill
// 162 MB of scratch — the attribute, not the geometry, was the bug.
// Per-block structure = r11: wave w owns gate-tiles {w,8+w,16+w,24+w} =
// i,f,g,o of units 16w..16w+15; in-register D-layout pointwise via sel4;
// folded decoder (K=128) with concurrent proj on waves 4-7; 1 barrier/step.
// Frag layouts (validated r4-r12):
//   A: lane l holds A[l&15][(l>>4)*8+j]   B: lane l holds B[(l>>4)*8+j][l&15]
//   D: lane l reg r = D[(l>>4)*4+r][l&15]
__global__ __launch_bounds__(512)
__attribute__((amdgpu_waves_per_eu(2)))
void lstm_ae_kernel(
    const float* __restrict__ ts,
    const float* __restrict__ Wih_e, const float* __restrict__ Whh_e,
    const float* __restrict__ bih_e, const float* __restrict__ bhh_e,
    const float* __restrict__ Wout, const float* __restrict__ bout,
    const f16* __restrict__ Wcomb, const float* __restrict__ bfold,
    float* __restrict__ out)
{
    const int tid = threadIdx.x;
    const int bid = blockIdx.x;
    const int row0 = bid * 2;

    const int wv = tid >> 6;       // wave 0..7 (owns units wv*16..wv*16+15)
    const int ln = tid & 63;
    const int n16 = ln & 15;       // MFMA N col (batch col; <2 real)
    const int kg = ln >> 4;        // k-group 0..3 (D rows kg*4..kg*4+3)
    const int zr = n16 & 1;        // batch row alias for B-frag
    const bool act2 = (n16 < 2);
    const bool pw = (n16 < 8);     // pointwise-active lanes (32/wave)
    const int us = (n16 >> 1) & 3; // D-reg select for pointwise
    const int un = kg * 4 + us;    // pointwise unit (wv*16+un), col n16&1

    __shared__ alignas(16) f16 hT[2][2][144];        // h dbuf
    __shared__ alignas(16) f16 xS[2][2][8][76];      // x chunk dbuf
    __shared__ float errb[4][2];

    float c_ = 0.f;    // one unit (wv*16+un), one batch col (n16&1)
    float bs[4];       // bias for that unit, gates i,f,g,o

    // ===================== encoder setup =====================
    f16x8 wf[4][6];   // A-frags [gate][k-tile], 96 VGPR
#pragma unroll
    for (int g = 0; g < 4; ++g) {
        const int gr = g * 128 + wv * 16 + n16;
#pragma unroll
        for (int kt = 0; kt < 6; ++kt) {
            const int kc = kt * 32 + kg * 8;
            const float* src = (kt < 2)
                ? (Wih_e + (size_t)gr * Fq + kc)
                : (Whh_e + (size_t)gr * Hq + (kc - 64));
            float4 f0 = *(const float4*)src;
            float4 f1 = *(const float4*)(src + 4);
            f16x8 a;
            a[0] = (f16)f0.x; a[1] = (f16)f0.y; a[2] = (f16)f0.z; a[3] = (f16)f0.w;
            a[4] = (f16)f1.x; a[5] = (f16)f1.y; a[6] = (f16)f1.z; a[7] = (f16)f1.w;
            wf[g][kt] = a;
        }
        bs[g] = bih_e[g * 128 + wv * 16 + un] + bhh_e[g * 128 + wv * 16 + un];
    }

    // zero h buffer 0 (both rows)
    if (act2) {
        f16x4 z; z[0] = (f16)0.f; z[1] = (f16)0.f; z[2] = (f16)0.f; z[3] = (f16)0.f;
        *(f16x4*)(&hT[0][n16][wv * 16 + kg * 4]) = z;
    }
    // stage x chunk 0 (256 threads): thread -> (r, t8, fg)
    const int t2 = tid & 255;
    const int sr = t2 >> 7, st8 = (t2 >> 4) & 7, sfg = t2 & 15;
    if (tid < 256) {
        float4 v = *(const float4*)(ts + (size_t)(row0 + sr) * Tq * Fq +
                                    (size_t)st8 * Fq + sfg * 4);
        f16x4 h4; h4[0] = (f16)v.x; h4[1] = (f16)v.y; h4[2] = (f16)v.z; h4[3] = (f16)v.w;
        *(f16x4*)(&xS[0][sr][st8][sfg * 4]) = h4;
    }
    __syncthreads();

    // ===================== encoder: 512 steps, 1 barrier each ============
    float4 xpre;
    for (int t = 0; t < Tq; ++t) {
        const int buf = (t >> 3) & 1, tb = t & 7, par = t & 1;
        if (tid < 256 && tb == 0 && t < Tq - 8) {  // issue chunk c+1 loads
            xpre = *(const float4*)(ts + (size_t)(row0 + sr) * Tq * Fq +
                                    (size_t)(t + 8 + st8) * Fq + sfg * 4);
        }
        f16x8 bf[6];
        bf[0] = *(const f16x8*)(&xS[buf][zr][tb][kg * 8]);
        bf[1] = *(const f16x8*)(&xS[buf][zr][tb][32 + kg * 8]);
#pragma unroll
        for (int kt = 0; kt < 4; ++kt)
            bf[2 + kt] = *(const f16x8*)(&hT[par][zr][kt * 32 + kg * 8]);
        f32x4 acc[4];
#pragma unroll
        for (int g = 0; g < 4; ++g) acc[g] = (f32x4){0.f, 0.f, 0.f, 0.f};
#pragma unroll
        for (int kt = 0; kt < 6; ++kt)
#pragma unroll
            for (int g = 0; g < 4; ++g)
                acc[g] = __builtin_amdgcn_mfma_f32_16x16x32_f16(
                    wf[g][kt], bf[kt], acc[g], 0, 0, 0);
        {   // in-register pointwise: lanes n16<8, one (unit, col) each
            float gi = sel4(acc[0], us) + bs[0];
            float gf = sel4(acc[1], us) + bs[1];
            float gg = sel4(acc[2], us) + bs[2];
            float go = sel4(acc[3], us) + bs[3];
            float i_ = sigmoidf_(gi);
            float f_ = sigmoidf_(gf);
            float g_ = tanhf_(gg);
            float o_ = sigmoidf_(go);
            c_ = f_ * c_ + i_ * g_;
            if (pw)
                hT[par ^ 1][n16 & 1][wv * 16 + un] = (f16)(o_ * tanhf_(c_));
        }
        if (tid < 256 && tb == 7 && t != Tq - 1) {  // publish staged chunk
            f16x4 h4; h4[0] = (f16)xpre.x; h4[1] = (f16)xpre.y;
            h4[2] = (f16)xpre.z; h4[3] = (f16)xpre.w;
            *(f16x4*)(&xS[buf ^ 1][sr][st8][sfg * 4]) = h4;
        }
        __syncthreads();
    }

    // c_enc: pw lanes own unit wv*16+un of batch row n16&1
    if (pw) out[(size_t)(row0 + (n16 & 1)) * Hq + wv * 16 + un] = c_;

    // ===================== decoder setup =====================
    f16x8 wc[4][4];   // folded weights straight from ws: 16 x 16B loads
#pragma unroll
    for (int g = 0; g < 4; ++g) {
        const int gr = g * 128 + wv * 16 + n16;
#pragma unroll
        for (int kt = 0; kt < 4; ++kt)
            wc[g][kt] = *(const f16x8*)(Wcomb + (size_t)gr * Hq + kt * 32 + kg * 8);
        bs[g] = bfold[g * 128 + wv * 16 + un];
    }
    // proj A-frags (waves 4..7 use them; mt=wv&3 keeps addresses valid)
    const int mt = wv & 3;
    f16x8 wo[4];
#pragma unroll
    for (int kt = 0; kt < 4; ++kt) {
        const float* src = Wout + (size_t)(mt * 16 + n16) * Hq + kt * 32 + kg * 8;
        float4 f0 = *(const float4*)src;
        float4 f1 = *(const float4*)(src + 4);
        f16x8 a;
        a[0] = (f16)f0.x; a[1] = (f16)f0.y; a[2] = (f16)f0.z; a[3] = (f16)f0.w;
        a[4] = (f16)f1.x; a[5] = (f16)f1.y; a[6] = (f16)f1.z; a[7] = (f16)f1.w;
        wo[kt] = a;
    }
    float4 bo4 = *(const float4*)(bout + mt * 16 + kg * 4);
    float4 tsv = *(const float4*)(ts + (size_t)(row0 + zr) * Tq * Fq +
                                  (size_t)(Tq - 1) * Fq + mt * 16 + kg * 4);
    float err_ = 0.f;
    __syncthreads();

    // ===================== decoder: 512 steps, 1 barrier each ============
    for (int k = 0; k < Tq; ++k) {
        const int pk = k & 1;
        f16x8 bf[4];
#pragma unroll
        for (int kt = 0; kt < 4; ++kt)
            bf[kt] = *(const f16x8*)(&hT[pk][zr][kt * 32 + kg * 8]);
        f32x4 acc[4];
#pragma unroll
        for (int g = 0; g < 4; ++g) acc[g] = (f32x4){0.f, 0.f, 0.f, 0.f};
#pragma unroll
        for (int kt = 0; kt < 4; ++kt)
#pragma unroll
            for (int g = 0; g < 4; ++g)
                acc[g] = __builtin_amdgcn_mfma_f32_16x16x32_f16(
                    wc[g][kt], bf[kt], acc[g], 0, 0, 0);
        if (wv >= 4) {   // concurrent projection of h[pk] for rec_err
            f32x4 pacc = (f32x4){0.f, 0.f, 0.f, 0.f};
#pragma unroll
            for (int kt = 0; kt < 4; ++kt)
                pacc = __builtin_amdgcn_mfma_f32_16x16x32_f16(
                    wo[kt], bf[kt], pacc, 0, 0, 0);
            if (act2) {
                float a0 = pacc[0] + bo4.x, a1 = pacc[1] + bo4.y;
                float a2 = pacc[2] + bo4.z, a3 = pacc[3] + bo4.w;
                if (k == 0) {
                    float4 av; av.x = a0; av.y = a1; av.z = a2; av.w = a3;
                    *(float4*)(out + (size_t)Bq * Hq + Bq +
                               (size_t)(row0 + n16) * Fq + mt * 16 + kg * 4) = av;
                }
                err_ += fabsf(a0 * a0 - tsv.x * tsv.x);
                err_ += fabsf(a1 * a1 - tsv.y * tsv.y);
                err_ += fabsf(a2 * a2 - tsv.z * tsv.z);
                err_ += fabsf(a3 * a3 - tsv.w * tsv.w);
                if (k < Tq - 1)
                    tsv = *(const float4*)(ts + (size_t)(row0 + n16) * Tq * Fq +
                                           (size_t)(Tq - 2 - k) * Fq +
                                           mt * 16 + kg * 4);
            }
        }
        {   // in-register pointwise
            float gi = sel4(acc[0], us) + bs[0];
            float gf = sel4(acc[1], us) + bs[1];
            float gg = sel4(acc[2], us) + bs[2];
            float go = sel4(acc[3], us) + bs[3];
            float i_ = sigmoidf_(gi);
            float f_ = sigmoidf_(gf);
            float g_ = tanhf_(gg);
            float o_ = sigmoidf_(go);
            c_ = f_ * c_ + i_ * g_;
            if (pw)
                hT[pk ^ 1][n16 & 1][wv * 16 + un] = (f16)(o_ * tanhf_(c_));
        }
        __syncthreads();
    }

    // rec_err reduction: waves 4..7 hold per-(row,f-slice) partials
    if (wv >= 4) {
        err_ += __shfl_xor(err_, 16, 64);   // sum over kg bit 0
        err_ += __shfl_xor(err_, 32, 64);   // sum over kg bit 1
        if (kg == 0 && act2) errb[mt][n16] = err_;
    }
    __syncthreads();
    if (tid < 2) {
        float e = errb[0][tid] + errb[1][tid] + errb[2][tid] + errb[3][tid];
        out[(size_t)Bq * Hq + row0 + tid] = e;
    }
}

extern "C" void kernel_launch(void* const* d_in, const int* in_sizes, int n_in,
                              void* d_out, int out_size, void* d_ws, size_t ws_size,
                              hipStream_t stream) {
    const float* ts    = (const float*)d_in[0];
    const float* Wih_e = (const float*)d_in[1];
    const float* Whh_e = (const float*)d_in[2];
    const float* bih_e = (const float*)d_in[3];
    const float* bhh_e = (const float*)d_in[4];
    const float* Wih_d = (const float*)d_in[5];
    const float* Whh_d = (const float*)d_in[6];
    const float* bih_d = (const float*)d_in[7];
    const float* bhh_d = (const float*)d_in[8];
    const float* Wout  = (const float*)d_in[9];
    const float* bout  = (const float*)d_in[10];
    float* out = (float*)d_out;

    f16*   Wcomb = (f16*)d_ws;                                   // 128 KB
    float* bfold = (float*)((char*)d_ws + (size_t)512 * 128 * 2); // +2 KB

    hipLaunchKernelGGL(fold_kernel, dim3(128), dim3(256), 0, stream,
                       Wih_d, Whh_d, bih_d, bhh_d, Wout, bout, Wcomb, bfold);
    hipLaunchKernelGGL(lstm_ae_kernel, dim3(Bq / 2), dim3(512), 0, stream,
                       ts, Wih_e, Whh_e, bih_e, bhh_e,
                       Wout, bout, Wcomb, bfold, out);
}

// Round 14
// 865.798 us; speedup vs baseline: 2.0155x; 1.6995x over previous
//
#include <hip/hip_runtime.h>

// Problem constants
#define Bq 1024
#define Tq 512
#define Fq 64    // input features
#define Hq 128   // hidden

typedef _Float16 f16;
typedef f16 f16x2 __attribute__((ext_vector_type(2)));
typedef f16 f16x4 __attribute__((ext_vector_type(4)));
typedef f16 f16x8 __attribute__((ext_vector_type(8)));
typedef float f32x4 __attribute__((ext_vector_type(4)));

__device__ __forceinline__ float sigmoidf_(float x) {
    return 1.f / (1.f + __expf(-x));
}
__device__ __forceinline__ float tanhf_(float x) {
    return 1.f - 2.f / (__expf(2.f * x) + 1.f);
}

// compile-time-indexed select of one element of an f32x4 (3 cndmasks)
__device__ __forceinline__ float sel4(f32x4 v, int s) {
    float r = v.x;
    r = (s == 1) ? v.y : r;
    r = (s == 2) ? v.z : r;
    r = (s == 3) ? v.w : r;
    return r;
}

// ---------------- kernel A: decoder fold (one-time, tiny) ----------------
// W_comb = W_ih_dec @ W_out + W_hh_dec   (f16, [512][128])
// b_fold = b_ih_dec + b_hh_dec + W_ih_dec @ b_out   (f32, [512])
__global__ __launch_bounds__(256) void fold_kernel(
    const float* __restrict__ Wih_d, const float* __restrict__ Whh_d,
    const float* __restrict__ bih_d, const float* __restrict__ bhh_d,
    const float* __restrict__ Wout, const float* __restrict__ bout,
    f16* __restrict__ Wcomb, float* __restrict__ bfold)
{
    const int gid = blockIdx.x * 256 + threadIdx.x;   // 0..32767
    const int og = gid >> 6;          // gate row 0..511
    const int oh = (gid & 63) * 2;    // hh pair
    float ax = Whh_d[(size_t)og * Hq + oh];
    float ay = Whh_d[(size_t)og * Hq + oh + 1];
    for (int f = 0; f < Fq; ++f) {
        float w = Wih_d[(size_t)og * Fq + f];
        float2 o = *(const float2*)(Wout + (size_t)f * Hq + oh);
        ax += w * o.x; ay += w * o.y;
    }
    f16x2 r; r.x = (f16)ax; r.y = (f16)ay;
    *(f16x2*)(Wcomb + (size_t)og * Hq + oh) = r;
    if (gid < 512) {
        float b = bih_d[gid] + bhh_d[gid];
        for (int f = 0; f < Fq; ++f)
            b += Wih_d[(size_t)gid * Fq + f] * bout[f];
        bfold[gid] = b;
    }
}

// ---------------- kernel B: main recurrence ----------------
// 256 blocks x 512 threads (8 waves), 4 batch rows per block, one block/CU
// (empirical: the dispatcher never co-places our 8-wave barrier blocks —
// r10/r12/r13 — so VGPR up to ~250 is free at 2 waves/SIMD).
// r11 structure + three serial-chain cuts:
//  1. x-part MFMA (k-tiles 0-1) hoisted to loop bottom: next step's acc is
//     pre-computed off the critical path (x known 8 steps ahead); chunk
//     publish moved tb7->tb6 so the next chunk is a barrier older than use.
//  2. bias as MFMA C-initializer (bias4[g] f32x4) — no per-step acc zeroing,
//     no bias adds after sel4.
//  3. h-MFMA chain split 2+2 (acc/accB + one vector add): depth 4 -> 2.
// Decoder gets the same treatment (bias4d / bo4 C-init, 2+2 splits).
// Frag layouts (validated r4-r13):
//   A: lane l holds A[l&15][(l>>4)*8+j]   B: lane l holds B[(l>>4)*8+j][l&15]
//   D: lane l reg r = D[(l>>4)*4+r][l&15]
__global__ __launch_bounds__(512)
__attribute__((amdgpu_waves_per_eu(2)))
void lstm_ae_kernel(
    const float* __restrict__ ts,
    const float* __restrict__ Wih_e, const float* __restrict__ Whh_e,
    const float* __restrict__ bih_e, const float* __restrict__ bhh_e,
    const float* __restrict__ Wout, const float* __restrict__ bout,
    const f16* __restrict__ Wcomb, const float* __restrict__ bfold,
    float* __restrict__ out)
{
    const int tid = threadIdx.x;
    const int bid = blockIdx.x;
    const int row0 = bid * 4;

    const int wv = tid >> 6;       // wave 0..7 (owns units wv*16..wv*16+15)
    const int ln = tid & 63;
    const int n16 = ln & 15;       // MFMA N col (batch col; <4 real)
    const int kg = ln >> 4;        // k-group 0..3 (D rows kg*4..kg*4+3)
    const int zr = n16 & 3;        // batch row for B-frag AND pointwise col
    const bool act = (n16 < 4);
    const int us = n16 >> 2;       // D-reg select: this lane's unit sub-index
    const int un = kg * 4 + us;    // pointwise: unit (wv*16+un), col zr

    __shared__ alignas(16) f16 hT[2][4][144];        // h dbuf
    __shared__ alignas(16) f16 xS[2][4][8][76];      // x chunk dbuf
    __shared__ float errb[4][4];

    float c_ = 0.f;     // one unit (wv*16+un), one batch col (zr)
    f32x4 bias4[4];     // bias for D rows kg*4..kg*4+3 of each gate (C-init)
    const f32x4 zero4 = (f32x4){0.f, 0.f, 0.f, 0.f};

    // ===================== encoder setup =====================
    f16x8 wf[4][6];   // A-frags [gate][k-tile], 96 VGPR
#pragma unroll
    for (int g = 0; g < 4; ++g) {
        const int gr = g * 128 + wv * 16 + n16;
#pragma unroll
        for (int kt = 0; kt < 6; ++kt) {
            const int kc = kt * 32 + kg * 8;
            const float* src = (kt < 2)
                ? (Wih_e + (size_t)gr * Fq + kc)
                : (Whh_e + (size_t)gr * Hq + (kc - 64));
            float4 f0 = *(const float4*)src;
            float4 f1 = *(const float4*)(src + 4);
            f16x8 a;
            a[0] = (f16)f0.x; a[1] = (f16)f0.y; a[2] = (f16)f0.z; a[3] = (f16)f0.w;
            a[4] = (f16)f1.x; a[5] = (f16)f1.y; a[6] = (f16)f1.z; a[7] = (f16)f1.w;
            wf[g][kt] = a;
        }
        f32x4 b1 = *(const f32x4*)(bih_e + g * 128 + wv * 16 + kg * 4);
        f32x4 b2 = *(const f32x4*)(bhh_e + g * 128 + wv * 16 + kg * 4);
        bias4[g] = b1 + b2;
    }

    // zero h buffer 0
    if (act) {
        f16x4 z; z[0] = (f16)0.f; z[1] = (f16)0.f; z[2] = (f16)0.f; z[3] = (f16)0.f;
        *(f16x4*)(&hT[0][n16][wv * 16 + kg * 4]) = z;
    }
    // stage x chunk 0: thread -> (r, t8, fg), all 512 threads
    const int sr = tid >> 7, st8 = (tid >> 4) & 7, sfg = tid & 15;
    {
        float4 v = *(const float4*)(ts + (size_t)(row0 + sr) * Tq * Fq +
                                    (size_t)st8 * Fq + sfg * 4);
        f16x4 h4; h4[0] = (f16)v.x; h4[1] = (f16)v.y; h4[2] = (f16)v.z; h4[3] = (f16)v.w;
        *(f16x4*)(&xS[0][sr][st8][sfg * 4]) = h4;
    }
    __syncthreads();

    // prologue: x-part of step 0 (bias as C-init)
    f32x4 acc[4];
    {
        f16x8 bx0 = *(const f16x8*)(&xS[0][zr][0][kg * 8]);
        f16x8 bx1 = *(const f16x8*)(&xS[0][zr][0][32 + kg * 8]);
#pragma unroll
        for (int g = 0; g < 4; ++g) {
            acc[g] = __builtin_amdgcn_mfma_f32_16x16x32_f16(wf[g][0], bx0, bias4[g], 0, 0, 0);
            acc[g] = __builtin_amdgcn_mfma_f32_16x16x32_f16(wf[g][1], bx1, acc[g], 0, 0, 0);
        }
    }

    // ===================== encoder: 512 steps, 1 barrier each ============
    float4 xpre;
    for (int t = 0; t < Tq; ++t) {
        const int buf = (t >> 3) & 1, tb = t & 7, par = t & 1;
        if (tb == 0 && t < Tq - 8) {   // issue chunk c+1 loads (8 steps slack)
            xpre = *(const float4*)(ts + (size_t)(row0 + sr) * Tq * Fq +
                                    (size_t)(t + 8 + st8) * Fq + sfg * 4);
        }
        // h-part: 4 tiles, 2+2 split chains on top of pre-computed x-part
        f16x8 bh0 = *(const f16x8*)(&hT[par][zr][kg * 8]);
        f16x8 bh1 = *(const f16x8*)(&hT[par][zr][32 + kg * 8]);
        f16x8 bh2 = *(const f16x8*)(&hT[par][zr][64 + kg * 8]);
        f16x8 bh3 = *(const f16x8*)(&hT[par][zr][96 + kg * 8]);
        f32x4 accB[4];
#pragma unroll
        for (int g = 0; g < 4; ++g) {
            acc[g]  = __builtin_amdgcn_mfma_f32_16x16x32_f16(wf[g][2], bh0, acc[g], 0, 0, 0);
            accB[g] = __builtin_amdgcn_mfma_f32_16x16x32_f16(wf[g][4], bh2, zero4, 0, 0, 0);
            acc[g]  = __builtin_amdgcn_mfma_f32_16x16x32_f16(wf[g][3], bh1, acc[g], 0, 0, 0);
            accB[g] = __builtin_amdgcn_mfma_f32_16x16x32_f16(wf[g][5], bh3, accB[g], 0, 0, 0);
            acc[g] = acc[g] + accB[g];
        }
        {   // in-register pointwise: every lane owns (unit un, col zr)
            float gi = sel4(acc[0], us);
            float gf = sel4(acc[1], us);
            float gg = sel4(acc[2], us);
            float go = sel4(acc[3], us);
            float i_ = sigmoidf_(gi);
            float f_ = sigmoidf_(gf);
            float g_ = tanhf_(gg);
            float o_ = sigmoidf_(go);
            c_ = f_ * c_ + i_ * g_;
            hT[par ^ 1][zr][wv * 16 + un] = (f16)(o_ * tanhf_(c_));
        }
        // bottom: pre-compute x-part for step t+1 (off the critical path)
        if (t < Tq - 1) {
            const int tb2 = (tb == 7) ? 0 : tb + 1;
            const int buf2 = (tb == 7) ? (buf ^ 1) : buf;
            f16x8 bx0 = *(const f16x8*)(&xS[buf2][zr][tb2][kg * 8]);
            f16x8 bx1 = *(const f16x8*)(&xS[buf2][zr][tb2][32 + kg * 8]);
#pragma unroll
            for (int g = 0; g < 4; ++g) {
                acc[g] = __builtin_amdgcn_mfma_f32_16x16x32_f16(wf[g][0], bx0, bias4[g], 0, 0, 0);
                acc[g] = __builtin_amdgcn_mfma_f32_16x16x32_f16(wf[g][1], bx1, acc[g], 0, 0, 0);
            }
        }
        if (tb == 6 && t < Tq - 8) {   // publish staged chunk (1 barrier early)
            f16x4 h4; h4[0] = (f16)xpre.x; h4[1] = (f16)xpre.y;
            h4[2] = (f16)xpre.z; h4[3] = (f16)xpre.w;
            *(f16x4*)(&xS[buf ^ 1][sr][st8][sfg * 4]) = h4;
        }
        __syncthreads();
    }

    // c_enc: thread owns unit wv*16+un of batch row zr
    out[(size_t)(row0 + zr) * Hq + wv * 16 + un] = c_;

    // ===================== decoder setup =====================
    f16x8 wc[4][4];   // folded weights straight from ws: 16 x 16B loads
#pragma unroll
    for (int g = 0; g < 4; ++g) {
        const int gr = g * 128 + wv * 16 + n16;
#pragma unroll
        for (int kt = 0; kt < 4; ++kt)
            wc[g][kt] = *(const f16x8*)(Wcomb + (size_t)gr * Hq + kt * 32 + kg * 8);
        bias4[g] = *(const f32x4*)(bfold + g * 128 + wv * 16 + kg * 4);
    }
    // proj A-frags (waves 4..7 use them; mt=wv&3 keeps addresses valid)
    const int mt = wv & 3;
    f16x8 wo[4];
#pragma unroll
    for (int kt = 0; kt < 4; ++kt) {
        const float* src = Wout + (size_t)(mt * 16 + n16) * Hq + kt * 32 + kg * 8;
        float4 f0 = *(const float4*)src;
        float4 f1 = *(const float4*)(src + 4);
        f16x8 a;
        a[0] = (f16)f0.x; a[1] = (f16)f0.y; a[2] = (f16)f0.z; a[3] = (f16)f0.w;
        a[4] = (f16)f1.x; a[5] = (f16)f1.y; a[6] = (f16)f1.z; a[7] = (f16)f1.w;
        wo[kt] = a;
    }
    f32x4 bo4 = *(const f32x4*)(bout + mt * 16 + kg * 4);
    float4 tsv = *(const float4*)(ts + (size_t)(row0 + zr) * Tq * Fq +
                                  (size_t)(Tq - 1) * Fq + mt * 16 + kg * 4);
    float err_ = 0.f;
    __syncthreads();

    // ===================== decoder: 512 steps, 1 barrier each ============
    for (int k = 0; k < Tq; ++k) {
        const int pk = k & 1;
        f16x8 bh0 = *(const f16x8*)(&hT[pk][zr][kg * 8]);
        f16x8 bh1 = *(const f16x8*)(&hT[pk][zr][32 + kg * 8]);
        f16x8 bh2 = *(const f16x8*)(&hT[pk][zr][64 + kg * 8]);
        f16x8 bh3 = *(const f16x8*)(&hT[pk][zr][96 + kg * 8]);
        f32x4 acc2[4], accB[4];
#pragma unroll
        for (int g = 0; g < 4; ++g) {
            acc2[g] = __builtin_amdgcn_mfma_f32_16x16x32_f16(wc[g][0], bh0, bias4[g], 0, 0, 0);
            accB[g] = __builtin_amdgcn_mfma_f32_16x16x32_f16(wc[g][2], bh2, zero4, 0, 0, 0);
            acc2[g] = __builtin_amdgcn_mfma_f32_16x16x32_f16(wc[g][1], bh1, acc2[g], 0, 0, 0);
            accB[g] = __builtin_amdgcn_mfma_f32_16x16x32_f16(wc[g][3], bh3, accB[g], 0, 0, 0);
            acc2[g] = acc2[g] + accB[g];
        }
        if (wv >= 4) {   // concurrent projection of h[pk] for rec_err
            f32x4 pA = __builtin_amdgcn_mfma_f32_16x16x32_f16(wo[0], bh0, bo4, 0, 0, 0);
            f32x4 pB = __builtin_amdgcn_mfma_f32_16x16x32_f16(wo[2], bh2, zero4, 0, 0, 0);
            pA = __builtin_amdgcn_mfma_f32_16x16x32_f16(wo[1], bh1, pA, 0, 0, 0);
            pB = __builtin_amdgcn_mfma_f32_16x16x32_f16(wo[3], bh3, pB, 0, 0, 0);
            f32x4 pacc = pA + pB;
            if (act) {
                float a0 = pacc[0], a1 = pacc[1], a2 = pacc[2], a3 = pacc[3];
                if (k == 0) {
                    float4 av; av.x = a0; av.y = a1; av.z = a2; av.w = a3;
                    *(float4*)(out + (size_t)Bq * Hq + Bq +
                               (size_t)(row0 + n16) * Fq + mt * 16 + kg * 4) = av;
                }
                err_ += fabsf(a0 * a0 - tsv.x * tsv.x);
                err_ += fabsf(a1 * a1 - tsv.y * tsv.y);
                err_ += fabsf(a2 * a2 - tsv.z * tsv.z);
                err_ += fabsf(a3 * a3 - tsv.w * tsv.w);
                if (k < Tq - 1)
                    tsv = *(const float4*)(ts + (size_t)(row0 + n16) * Tq * Fq +
                                           (size_t)(Tq - 2 - k) * Fq +
                                           mt * 16 + kg * 4);
            }
        }
        {   // in-register pointwise
            float gi = sel4(acc2[0], us);
            float gf = sel4(acc2[1], us);
            float gg = sel4(acc2[2], us);
            float go = sel4(acc2[3], us);
            float i_ = sigmoidf_(gi);
            float f_ = sigmoidf_(gf);
            float g_ = tanhf_(gg);
            float o_ = sigmoidf_(go);
            c_ = f_ * c_ + i_ * g_;
            hT[pk ^ 1][zr][wv * 16 + un] = (f16)(o_ * tanhf_(c_));
        }
        __syncthreads();
    }

    // rec_err reduction: waves 4..7 hold per-(row,f-slice) partials
    if (wv >= 4) {
        err_ += __shfl_xor(err_, 16, 64);   // sum over kg bit 0
        err_ += __shfl_xor(err_, 32, 64);   // sum over kg bit 1
        if (kg == 0 && act) errb[mt][n16] = err_;
    }
    __syncthreads();
    if (tid < 4) {
        float e = errb[0][tid] + errb[1][tid] + errb[2][tid] + errb[3][tid];
        out[(size_t)Bq * Hq + row0 + tid] = e;
    }
}

extern "C" void kernel_launch(void* const* d_in, const int* in_sizes, int n_in,
                              void* d_out, int out_size, void* d_ws, size_t ws_size,
                              hipStream_t stream) {
    const float* ts    = (const float*)d_in[0];
    const float* Wih_e = (const float*)d_in[1];
    const float* Whh_e = (const float*)d_in[2];
    const float* bih_e = (const float*)d_in[3];
    const float* bhh_e = (const float*)d_in[4];
    const float* Wih_d = (const float*)d_in[5];
    const float* Whh_d = (const float*)d_in[6];
    const float* bih_d = (const float*)d_in[7];
    const float* bhh_d = (const float*)d_in[8];
    const float* Wout  = (const float*)d_in[9];
    const float* bout  = (const float*)d_in[10];
    float* out = (float*)d_out;

    f16*   Wcomb = (f16*)d_ws;                                   // 128 KB
    float* bfold = (float*)((char*)d_ws + (size_t)512 * 128 * 2); // +2 KB

    hipLaunchKernelGGL(fold_kernel, dim3(128), dim3(256), 0, stream,
                       Wih_d, Whh_d, bih_d, bhh_d, Wout, bout, Wcomb, bfold);
    hipLaunchKernelGGL(lstm_ae_kernel, dim3(Bq / 4), dim3(512), 0, stream,
                       ts, Wih_e, Whh_e, bih_e, bhh_e,
                       Wout, bout, Wcomb, bfold, out);
}

// Round 15
// 604.053 us; speedup vs baseline: 2.8889x; 1.4333x over previous
//
#include <hip/hip_runtime.h>

// Problem constants
#define Bq 1024
#define Tq 512
#define Fq 64    // input features
#define Hq 128   // hidden
#define LOG2E 1.44269504089f
#define TWO_LOG2E 2.88539008177f

typedef _Float16 f16;
typedef f16 f16x2 __attribute__((ext_vector_type(2)));
typedef f16 f16x4 __attribute__((ext_vector_type(4)));
typedef f16 f16x8 __attribute__((ext_vector_type(8)));
typedef float f32x4 __attribute__((ext_vector_type(4)));

__device__ __forceinline__ float exp2f_(float x) {
#if __has_builtin(__builtin_amdgcn_exp2f)
    return __builtin_amdgcn_exp2f(x);
#else
    return __expf(x * 0.69314718056f);
#endif
}
__device__ __forceinline__ float rcpf_(float x) {
#if __has_builtin(__builtin_amdgcn_rcpf)
    return __builtin_amdgcn_rcpf(x);
#else
    return 1.f / x;
#endif
}

// compile-time-indexed select of one element of an f32x4 (3 cndmasks)
__device__ __forceinline__ float sel4(f32x4 v, int s) {
    float r = v.x;
    r = (s == 1) ? v.y : r;
    r = (s == 2) ? v.z : r;
    r = (s == 3) ? v.w : r;
    return r;
}

// ---------------- kernel A: decoder fold (one-time, tiny) ----------------
// W_comb = (W_ih_dec @ W_out + W_hh_dec) * lg  (f16, [512][128])
// b_fold = (b_ih+b_hh+W_ih_dec@b_out) * lg     (f32, [512])
// lg = log2e for i,f,o gates; 2*log2e for the g gate (exp2-based pointwise).
__global__ __launch_bounds__(256) void fold_kernel(
    const float* __restrict__ Wih_d, const float* __restrict__ Whh_d,
    const float* __restrict__ bih_d, const float* __restrict__ bhh_d,
    const float* __restrict__ Wout, const float* __restrict__ bout,
    f16* __restrict__ Wcomb, float* __restrict__ bfold)
{
    const int gid = blockIdx.x * 256 + threadIdx.x;   // 0..32767
    const int og = gid >> 6;          // gate row 0..511
    const int oh = (gid & 63) * 2;    // hh pair
    const float lg = ((og >> 7) == 2) ? TWO_LOG2E : LOG2E;
    float ax = Whh_d[(size_t)og * Hq + oh];
    float ay = Whh_d[(size_t)og * Hq + oh + 1];
    for (int f = 0; f < Fq; ++f) {
        float w = Wih_d[(size_t)og * Fq + f];
        float2 o = *(const float2*)(Wout + (size_t)f * Hq + oh);
        ax += w * o.x; ay += w * o.y;
    }
    f16x2 r; r.x = (f16)(ax * lg); r.y = (f16)(ay * lg);
    *(f16x2*)(Wcomb + (size_t)og * Hq + oh) = r;
    if (gid < 512) {
        const float lgb = ((gid >> 7) == 2) ? TWO_LOG2E : LOG2E;
        float b = bih_d[gid] + bhh_d[gid];
        for (int f = 0; f < Fq; ++f)
            b += Wih_d[(size_t)gid * Fq + f] * bout[f];
        bfold[gid] = b * lgb;
    }
}

// ---------------- kernel B: main recurrence ----------------
// 256 blocks x 512 threads (8 waves), 4 batch rows, 1 block/CU (structural:
// every block runs all 1024 steps, so occupancy is a dead axis — r12/r13).
// r11 base (in-register D-layout pointwise, folded decoder, 1 barrier/step)
// plus three step-time cuts:
//  1. rcp/exp2 pointwise with log2e FOLDED INTO WEIGHTS (kills 4 f32
//     divides = ~40 VALU/lane/step and shortens the transcendental chain).
//  2. x-batch: one x-pass per 4 steps computes x-partials for (row, t+dt)
//     in N-cols (col = dt*4+row), bounced via wave-private xg LDS;
//     x-MFMA per wave-step drops 8 -> 2 (matrix pipe ~930 -> ~700 cyc).
//  3. bias as MFMA C-init (encoder: x-pass; decoder: gate chain).
// Frag layouts (validated r4-r14):
//   A: lane l holds A[l&15][(l>>4)*8+j]   B: lane l holds B[(l>>4)*8+j][l&15]
//   D: lane l reg r = D[(l>>4)*4+r][l&15]
__global__ __launch_bounds__(512)
__attribute__((amdgpu_waves_per_eu(2)))
void lstm_ae_kernel(
    const float* __restrict__ ts,
    const float* __restrict__ Wih_e, const float* __restrict__ Whh_e,
    const float* __restrict__ bih_e, const float* __restrict__ bhh_e,
    const float* __restrict__ Wout, const float* __restrict__ bout,
    const f16* __restrict__ Wcomb, const float* __restrict__ bfold,
    float* __restrict__ out)
{
    const int tid = threadIdx.x;
    const int bid = blockIdx.x;
    const int row0 = bid * 4;

    const int wv = tid >> 6;       // wave 0..7 (owns units wv*16..wv*16+15)
    const int ln = tid & 63;
    const int n16 = ln & 15;       // MFMA N col
    const int kg = ln >> 4;        // k-group 0..3 (D rows kg*4..kg*4+3)
    const int zr = n16 & 3;        // batch row for B-frag AND pointwise col
    const bool act = (n16 < 4);
    const int us = n16 >> 2;       // D-reg select / x-pass time offset
    const int un = kg * 4 + us;    // pointwise: unit (wv*16+un), col zr

    __shared__ alignas(16) f16 hT[2][4][144];          // h dbuf
    __shared__ alignas(16) f16 xS[2][4][8][76];        // x chunk dbuf
    __shared__ alignas(16) float xg[8][4][4][4][16];   // x-partial bounce 32KB
    __shared__ float errb[4][4];

    float c_ = 0.f;     // one unit (wv*16+un), one batch col (zr)
    f32x4 bias4[4];     // scaled bias, C-init of the x-pass / decoder chain

    // ===================== encoder setup =====================
    f16x8 wf[4][6];   // A-frags [gate][k-tile], 96 VGPR (log2e-scaled)
#pragma unroll
    for (int g = 0; g < 4; ++g) {
        const float fg = (g == 2) ? TWO_LOG2E : LOG2E;
        const int gr = g * 128 + wv * 16 + n16;
#pragma unroll
        for (int kt = 0; kt < 6; ++kt) {
            const int kc = kt * 32 + kg * 8;
            const float* src = (kt < 2)
                ? (Wih_e + (size_t)gr * Fq + kc)
                : (Whh_e + (size_t)gr * Hq + (kc - 64));
            float4 f0 = *(const float4*)src;
            float4 f1 = *(const float4*)(src + 4);
            f16x8 a;
            a[0] = (f16)(f0.x * fg); a[1] = (f16)(f0.y * fg);
            a[2] = (f16)(f0.z * fg); a[3] = (f16)(f0.w * fg);
            a[4] = (f16)(f1.x * fg); a[5] = (f16)(f1.y * fg);
            a[6] = (f16)(f1.z * fg); a[7] = (f16)(f1.w * fg);
            wf[g][kt] = a;
        }
        f32x4 b1 = *(const f32x4*)(bih_e + g * 128 + wv * 16 + kg * 4);
        f32x4 b2 = *(const f32x4*)(bhh_e + g * 128 + wv * 16 + kg * 4);
        bias4[g] = (b1 + b2) * fg;
    }

    // zero h buffer 0
    if (act) {
        f16x4 z; z[0] = (f16)0.f; z[1] = (f16)0.f; z[2] = (f16)0.f; z[3] = (f16)0.f;
        *(f16x4*)(&hT[0][n16][wv * 16 + kg * 4]) = z;
    }
    // stage x chunk 0: thread -> (r, t8, fg)
    const int sr = tid >> 7, st8 = (tid >> 4) & 7, sfg = tid & 15;
    {
        float4 v = *(const float4*)(ts + (size_t)(row0 + sr) * Tq * Fq +
                                    (size_t)st8 * Fq + sfg * 4);
        f16x4 h4; h4[0] = (f16)v.x; h4[1] = (f16)v.y; h4[2] = (f16)v.z; h4[3] = (f16)v.w;
        *(f16x4*)(&xS[0][sr][st8][sfg * 4]) = h4;
    }
    __syncthreads();

    // ===================== encoder: 512 steps, 1 barrier each ============
    float4 xpre;
    f32x4 xacc[4];
    for (int t = 0; t < Tq; ++t) {
        const int buf = (t >> 3) & 1, tb = t & 7, par = t & 1, dt = t & 3;
        if (tb == 0 && t < Tq - 8) {   // issue chunk c+1 loads (8 steps slack)
            xpre = *(const float4*)(ts + (size_t)(row0 + sr) * Tq * Fq +
                                    (size_t)(t + 8 + st8) * Fq + sfg * 4);
        }
        if (dt == 0) {   // x-pass: 4 steps' x-partials across the 16 N-cols
            const int xt = tb + us;          // this col carries time t+us
            f16x8 bx0 = *(const f16x8*)(&xS[buf][zr][xt][kg * 8]);
            f16x8 bx1 = *(const f16x8*)(&xS[buf][zr][xt][32 + kg * 8]);
#pragma unroll
            for (int g = 0; g < 4; ++g) {
                xacc[g] = __builtin_amdgcn_mfma_f32_16x16x32_f16(
                    wf[g][0], bx0, bias4[g], 0, 0, 0);
                xacc[g] = __builtin_amdgcn_mfma_f32_16x16x32_f16(
                    wf[g][1], bx1, xacc[g], 0, 0, 0);
                *(f32x4*)(&xg[wv][g][us][zr][kg * 4]) = xacc[g];
            }
        }
        // C-init for this step from the wave-private bounce (col-redistribute)
        f32x4 acc[4];
#pragma unroll
        for (int g = 0; g < 4; ++g)
            acc[g] = *(const f32x4*)(&xg[wv][g][dt][zr][kg * 4]);
        // h-part: 4 tiles
        f16x8 bh0 = *(const f16x8*)(&hT[par][zr][kg * 8]);
        f16x8 bh1 = *(const f16x8*)(&hT[par][zr][32 + kg * 8]);
        f16x8 bh2 = *(const f16x8*)(&hT[par][zr][64 + kg * 8]);
        f16x8 bh3 = *(const f16x8*)(&hT[par][zr][96 + kg * 8]);
#pragma unroll
        for (int g = 0; g < 4; ++g) {
            acc[g] = __builtin_amdgcn_mfma_f32_16x16x32_f16(wf[g][2], bh0, acc[g], 0, 0, 0);
            acc[g] = __builtin_amdgcn_mfma_f32_16x16x32_f16(wf[g][3], bh1, acc[g], 0, 0, 0);
            acc[g] = __builtin_amdgcn_mfma_f32_16x16x32_f16(wf[g][4], bh2, acc[g], 0, 0, 0);
            acc[g] = __builtin_amdgcn_mfma_f32_16x16x32_f16(wf[g][5], bh3, acc[g], 0, 0, 0);
        }
        {   // pointwise (exp2-domain gates, rcp instead of divide)
            float gi = sel4(acc[0], us);
            float gf = sel4(acc[1], us);
            float gg = sel4(acc[2], us);
            float go = sel4(acc[3], us);
            float i_ = rcpf_(1.f + exp2f_(-gi));
            float f_ = rcpf_(1.f + exp2f_(-gf));
            float g_ = 1.f - 2.f * rcpf_(exp2f_(gg) + 1.f);
            float o_ = rcpf_(1.f + exp2f_(-go));
            c_ = f_ * c_ + i_ * g_;
            float th = 1.f - 2.f * rcpf_(exp2f_(c_ * TWO_LOG2E) + 1.f);
            hT[par ^ 1][zr][wv * 16 + un] = (f16)(o_ * th);
        }
        if (tb == 7 && t != Tq - 1) {  // publish staged chunk
            f16x4 h4; h4[0] = (f16)xpre.x; h4[1] = (f16)xpre.y;
            h4[2] = (f16)xpre.z; h4[3] = (f16)xpre.w;
            *(f16x4*)(&xS[buf ^ 1][sr][st8][sfg * 4]) = h4;
        }
        __syncthreads();
    }

    // c_enc: thread owns unit wv*16+un of batch row zr
    out[(size_t)(row0 + zr) * Hq + wv * 16 + un] = c_;

    // ===================== decoder setup =====================
    f16x8 wc[4][4];   // folded (scaled) weights from ws: 16 x 16B loads
#pragma unroll
    for (int g = 0; g < 4; ++g) {
        const int gr = g * 128 + wv * 16 + n16;
#pragma unroll
        for (int kt = 0; kt < 4; ++kt)
            wc[g][kt] = *(const f16x8*)(Wcomb + (size_t)gr * Hq + kt * 32 + kg * 8);
        bias4[g] = *(const f32x4*)(bfold + g * 128 + wv * 16 + kg * 4);
    }
    // proj A-frags (waves 4..7 use them; mt=wv&3 keeps addresses valid)
    const int mt = wv & 3;
    f16x8 wo[4];
#pragma unroll
    for (int kt = 0; kt < 4; ++kt) {
        const float* src = Wout + (size_t)(mt * 16 + n16) * Hq + kt * 32 + kg * 8;
        float4 f0 = *(const float4*)src;
        float4 f1 = *(const float4*)(src + 4);
        f16x8 a;
        a[0] = (f16)f0.x; a[1] = (f16)f0.y; a[2] = (f16)f0.z; a[3] = (f16)f0.w;
        a[4] = (f16)f1.x; a[5] = (f16)f1.y; a[6] = (f16)f1.z; a[7] = (f16)f1.w;
        wo[kt] = a;
    }
    f32x4 bo4 = *(const f32x4*)(bout + mt * 16 + kg * 4);
    float4 tsv = *(const float4*)(ts + (size_t)(row0 + zr) * Tq * Fq +
                                  (size_t)(Tq - 1) * Fq + mt * 16 + kg * 4);
    float err_ = 0.f;
    __syncthreads();

    // ===================== decoder: 512 steps, 1 barrier each ============
    for (int k = 0; k < Tq; ++k) {
        const int pk = k & 1;
        f16x8 bh0 = *(const f16x8*)(&hT[pk][zr][kg * 8]);
        f16x8 bh1 = *(const f16x8*)(&hT[pk][zr][32 + kg * 8]);
        f16x8 bh2 = *(const f16x8*)(&hT[pk][zr][64 + kg * 8]);
        f16x8 bh3 = *(const f16x8*)(&hT[pk][zr][96 + kg * 8]);
        f32x4 acc[4];
#pragma unroll
        for (int g = 0; g < 4; ++g) {
            acc[g] = __builtin_amdgcn_mfma_f32_16x16x32_f16(wc[g][0], bh0, bias4[g], 0, 0, 0);
            acc[g] = __builtin_amdgcn_mfma_f32_16x16x32_f16(wc[g][1], bh1, acc[g], 0, 0, 0);
            acc[g] = __builtin_amdgcn_mfma_f32_16x16x32_f16(wc[g][2], bh2, acc[g], 0, 0, 0);
            acc[g] = __builtin_amdgcn_mfma_f32_16x16x32_f16(wc[g][3], bh3, acc[g], 0, 0, 0);
        }
        if (wv >= 4) {   // concurrent projection of h[pk] for rec_err
            f32x4 pacc = __builtin_amdgcn_mfma_f32_16x16x32_f16(wo[0], bh0, bo4, 0, 0, 0);
            pacc = __builtin_amdgcn_mfma_f32_16x16x32_f16(wo[1], bh1, pacc, 0, 0, 0);
            pacc = __builtin_amdgcn_mfma_f32_16x16x32_f16(wo[2], bh2, pacc, 0, 0, 0);
            pacc = __builtin_amdgcn_mfma_f32_16x16x32_f16(wo[3], bh3, pacc, 0, 0, 0);
            if (act) {
                float a0 = pacc[0], a1 = pacc[1], a2 = pacc[2], a3 = pacc[3];
                if (k == 0) {
                    float4 av; av.x = a0; av.y = a1; av.z = a2; av.w = a3;
                    *(float4*)(out + (size_t)Bq * Hq + Bq +
                               (size_t)(row0 + n16) * Fq + mt * 16 + kg * 4) = av;
                }
                err_ += fabsf(a0 * a0 - tsv.x * tsv.x);
                err_ += fabsf(a1 * a1 - tsv.y * tsv.y);
                err_ += fabsf(a2 * a2 - tsv.z * tsv.z);
                err_ += fabsf(a3 * a3 - tsv.w * tsv.w);
                if (k < Tq - 1)
                    tsv = *(const float4*)(ts + (size_t)(row0 + n16) * Tq * Fq +
                                           (size_t)(Tq - 2 - k) * Fq +
                                           mt * 16 + kg * 4);
            }
        }
        {   // pointwise
            float gi = sel4(acc[0], us);
            float gf = sel4(acc[1], us);
            float gg = sel4(acc[2], us);
            float go = sel4(acc[3], us);
            float i_ = rcpf_(1.f + exp2f_(-gi));
            float f_ = rcpf_(1.f + exp2f_(-gf));
            float g_ = 1.f - 2.f * rcpf_(exp2f_(gg) + 1.f);
            float o_ = rcpf_(1.f + exp2f_(-go));
            c_ = f_ * c_ + i_ * g_;
            float th = 1.f - 2.f * rcpf_(exp2f_(c_ * TWO_LOG2E) + 1.f);
            hT[pk ^ 1][zr][wv * 16 + un] = (f16)(o_ * th);
        }
        __syncthreads();
    }

    // rec_err reduction: waves 4..7 hold per-(row,f-slice) partials
    if (wv >= 4) {
        err_ += __shfl_xor(err_, 16, 64);   // sum over kg bit 0
        err_ += __shfl_xor(err_, 32, 64);   // sum over kg bit 1
        if (kg == 0 && act) errb[mt][n16] = err_;
    }
    __syncthreads();
    if (tid < 4) {
        float e = errb[0][tid] + errb[1][tid] + errb[2][tid] + errb[3][tid];
        out[(size_t)Bq * Hq + row0 + tid] = e;
    }
}

extern "C" void kernel_launch(void* const* d_in, const int* in_sizes, int n_in,
                              void* d_out, int out_size, void* d_ws, size_t ws_size,
                              hipStream_t stream) {
    const float* ts    = (const float*)d_in[0];
    const float* Wih_e = (const float*)d_in[1];
    const float* Whh_e = (const float*)d_in[2];
    const float* bih_e = (const float*)d_in[3];
    const float* bhh_e = (const float*)d_in[4];
    const float* Wih_d = (const float*)d_in[5];
    const float* Whh_d = (const float*)d_in[6];
    const float* bih_d = (const float*)d_in[7];
    const float* bhh_d = (const float*)d_in[8];
    const float* Wout  = (const float*)d_in[9];
    const float* bout  = (const float*)d_in[10];
    float* out = (float*)d_out;

    f16*   Wcomb = (f16*)d_ws;                                   // 128 KB
    float* bfold = (float*)((char*)d_ws + (size_t)512 * 128 * 2); // +2 KB

    hipLaunchKernelGGL(fold_kernel, dim3(128), dim3(256), 0, stream,
                       Wih_d, Whh_d, bih_d, bhh_d, Wout, bout, Wcomb, bfold);
    hipLaunchKernelGGL(lstm_ae_kernel, dim3(Bq / 4), dim3(512), 0, stream,
                       ts, Wih_e, Whh_e, bih_e, bhh_e,
                       Wout, bout, Wcomb, bfold, out);
}